// Round 9
// baseline (216.377 us; speedup 1.0000x reference)
//
#include <hip/hip_runtime.h>
#include <math.h>

#define BDIM 16
#define LDIM 512
#define CDIM 1024
#define NH 8
#define HD 128
#define MROWS (BDIM * LDIM)   /* 8192 */
#define N3 (3 * CDIM)         /* 3072 */

typedef unsigned short u16;
typedef unsigned long long u64;
typedef short s8v __attribute__((ext_vector_type(8)));   // 8 bf16 = 4 VGPRs (MFMA A/B frag)
typedef short s4v __attribute__((ext_vector_type(4)));   // 4 bf16 = 2 VGPRs
typedef float f32x4 __attribute__((ext_vector_type(4))); // MFMA C/D frag

__device__ __forceinline__ float sigmoidf_(float z) {
    return 1.0f / (1.0f + __expf(-z));
}
__device__ __forceinline__ u16 f2bf(float f) {
    union { float f; unsigned int u; } v; v.f = f;
    unsigned int u = v.u;
    unsigned int r = (u + 0x7FFFu + ((u >> 16) & 1u)) >> 16;   // round-nearest-even
    return (u16)r;
}
__device__ __forceinline__ float bf2f(u16 b) {
    union { unsigned int u; float f; } v; v.u = ((unsigned int)b) << 16;
    return v.f;
}

// ---------------- Kernel 1: fused prep ----------------
// blocks [0, MROWS):       row r -> degree (block reduce) + adj bitmask pack + gate
// blocks [MROWS, +768):    packW tile: Wt[n][k] = bf16(W[k][n])
__global__ __launch_bounds__(256) void prep_kernel(const float* __restrict__ adj,
                                                   const float* __restrict__ x,
                                                   const float* __restrict__ Wd,
                                                   const float* __restrict__ bd,
                                                   const float* __restrict__ W,
                                                   u64* __restrict__ adjbits,
                                                   u16* __restrict__ xg,
                                                   u16* __restrict__ Wt) {
    __shared__ float tile[64][65];   // packW transpose tile; prep path uses tile[0][0..3]
    int bid = blockIdx.x;
    int t = threadIdx.x;
    if (bid < MROWS) {
        int row = bid;
        int lane = t & 63, w = t >> 6;
        const float* a = adj + (size_t)row * LDIM;
        float s = 0.f;
        #pragma unroll
        for (int j = 0; j < 2; ++j) {
            int mc = j * 256 + w * 64;              // word index mc>>6 = j*4 + w
            float v = a[mc + lane];
            s += v;
            u64 m = __ballot(v != 0.f);
            if (lane == 0) adjbits[(size_t)row * (LDIM / 64) + (mc >> 6)] = m;
        }
        #pragma unroll
        for (int off = 32; off > 0; off >>= 1) s += __shfl_down(s, off);
        if (lane == 0) tile[0][w] = s;
        __syncthreads();
        float d = tile[0][0] + tile[0][1] + tile[0][2] + tile[0][3];
        float4 xv = ((const float4*)(x + (size_t)row * CDIM))[t];
        float4 wv = ((const float4*)Wd)[t];
        float4 bv = ((const float4*)bd)[t];
        s4v o;
        o.x = (short)f2bf(xv.x * sigmoidf_(d * wv.x + bv.x));
        o.y = (short)f2bf(xv.y * sigmoidf_(d * wv.y + bv.y));
        o.z = (short)f2bf(xv.z * sigmoidf_(d * wv.z + bv.z));
        o.w = (short)f2bf(xv.w * sigmoidf_(d * wv.w + bv.w));
        ((s4v*)(xg + (size_t)row * CDIM))[t] = o;
    } else {
        int pb = bid - MROWS;
        int k0 = (pb & 15) * 64, n0 = (pb >> 4) * 64;
        int tx = t & 63, ty = t >> 6;  // ty 0..3
        #pragma unroll
        for (int yy = ty; yy < 64; yy += 4)
            tile[yy][tx] = W[(size_t)(k0 + yy) * N3 + n0 + tx];
        __syncthreads();
        #pragma unroll
        for (int yy = ty; yy < 64; yy += 4)
            Wt[(size_t)(n0 + yy) * CDIM + k0 + tx] = f2bf(tile[tx][yy]);
    }
}

// ---------------- Kernel 2: bf16 MFMA GEMM (m97-style), LDS-coalesced epilogue ------
// K-loop unchanged from the round-0 kernel (64.5-70 us; 8-phase falsified 3x).
// ROUND-9 CHANGE: epilogue writes were <=32B-contiguous scatters (vt: 8B per lane at
// 1KB stride) -> WRITE_SIZE 72MB vs 48MB of output = 50% write amplification.
// Fix: after the K-loop's final barrier As/Bs are dead; reuse the 32KB as a 128x128
// bf16 C-tile (smem merged). Pack acc (+bias, +sigmoid chunk0, transposed [d][l] for
// chunk2) into LDS with XOR swizzle pcol = col ^ ((row&7)<<4) (<=2-way conflicts),
// barrier, flush 8x16B per thread -> all global stores are coalesced 16B pieces of
// 256B rows. Each chunk0/2 block covers exactly one head (128 cols) and one bb.
__global__ __launch_bounds__(256, 3) void gemm_bf16_kernel(const u16* __restrict__ A,
                                                           const u16* __restrict__ Bt,
                                                           const float* __restrict__ bias,
                                                           u16* __restrict__ ksig,
                                                           u16* __restrict__ resb,
                                                           u16* __restrict__ vt) {
    __shared__ __align__(16) u16 smem[128 * 128];  // K-loop: A=[0,8192) B=[8192,16384); epilogue: C-tile
#define BOFF (128 * 64)
    int t = threadIdx.x;
    int m0 = blockIdx.y * 128, n0 = blockIdx.x * 128;
    int lane = t & 63, w = t >> 6;
    int i15 = lane & 15, quad = lane >> 4;
    int wm = w >> 1, wn = w & 1;

    f32x4 acc[4][4];
    #pragma unroll
    for (int i = 0; i < 4; ++i)
        #pragma unroll
        for (int j = 0; j < 4; ++j) acc[i][j] = (f32x4)(0.f);

    for (int k0 = 0; k0 < CDIM; k0 += 64) {
        #pragma unroll
        for (int p = 0; p < 4; ++p) {
            int sb = (w * 4 + p) * 64;           // wave-uniform slot base
            int s = sb + lane;
            int row = s >> 3;
            int seg = (s & 7) ^ (row & 7);       // global-side XOR swizzle
            const u16* ga = A + (size_t)(m0 + row) * CDIM + k0 + seg * 8;
            const u16* gb = Bt + (size_t)(n0 + row) * CDIM + k0 + seg * 8;
            __builtin_amdgcn_global_load_lds(
                (const __attribute__((address_space(1))) unsigned int*)ga,
                (__attribute__((address_space(3))) unsigned int*)&smem[sb * 8], 16, 0, 0);
            __builtin_amdgcn_global_load_lds(
                (const __attribute__((address_space(1))) unsigned int*)gb,
                (__attribute__((address_space(3))) unsigned int*)&smem[BOFF + sb * 8], 16, 0, 0);
        }
        __syncthreads();
        #pragma unroll
        for (int kc = 0; kc < 2; ++kc) {
            s8v aF[4], bF[4];
            #pragma unroll
            for (int mt = 0; mt < 4; ++mt) {
                int row = wm * 64 + mt * 16 + i15;
                int slot = row * 8 + ((kc * 4 + quad) ^ (i15 & 7));
                aF[mt] = *(const s8v*)&smem[slot * 8];
            }
            #pragma unroll
            for (int nt = 0; nt < 4; ++nt) {
                int row = wn * 64 + nt * 16 + i15;
                int slot = row * 8 + ((kc * 4 + quad) ^ (i15 & 7));
                bF[nt] = *(const s8v*)&smem[BOFF + slot * 8];
            }
            #pragma unroll
            for (int mt = 0; mt < 4; ++mt)
                #pragma unroll
                for (int nt = 0; nt < 4; ++nt)
                    acc[mt][nt] = __builtin_amdgcn_mfma_f32_16x16x32_bf16(aF[mt], bF[nt], acc[mt][nt], 0, 0, 0);
        }
        __syncthreads();   // last iteration: all As/Bs reads retired -> smem reusable
    }

    int chunk = n0 >> 10;
    // ---- pack acc -> LDS C-tile (swizzled; transposed for chunk 2) ----
    #pragma unroll
    for (int nt = 0; nt < 4; ++nt) {
        int lcol = wn * 64 + nt * 16 + i15;          // 0..127 within tile
        float bv = bias[n0 + lcol];
        #pragma unroll
        for (int mt = 0; mt < 4; ++mt) {
            int lrow0 = wm * 64 + mt * 16 + quad * 4;
            #pragma unroll
            for (int r = 0; r < 4; ++r) {
                int lrow = lrow0 + r;
                float v = acc[mt][nt][r] + bv;
                if (chunk == 0) v = sigmoidf_(v);
                u16 bf = f2bf(v);
                if (chunk == 2)
                    smem[lcol * 128 + (lrow ^ ((lcol & 7) << 4))] = bf;   // [d][l]
                else
                    smem[lrow * 128 + (lcol ^ ((lrow & 7) << 4))] = bf;   // [row][col]
            }
        }
    }
    __syncthreads();
    // ---- coalesced flush: 8 x 16B per thread ----
    if (chunk == 0) {
        int h = (n0 >> 7) & 7;
        int bb = m0 >> 9, lb = m0 & 511;
        #pragma unroll
        for (int i = 0; i < 8; ++i) {
            int idx = i * 2048 + t * 8;              // u16 units
            int row = idx >> 7, pc = idx & 127;
            int col = pc ^ ((row & 7) << 4);
            *(s8v*)&ksig[(((size_t)bb * NH + h) * LDIM + lb + row) * HD + col] =
                *(const s8v*)&smem[idx];
        }
    } else if (chunk == 1) {
        int c0 = n0 - CDIM;
        #pragma unroll
        for (int i = 0; i < 8; ++i) {
            int idx = i * 2048 + t * 8;
            int row = idx >> 7, pc = idx & 127;
            int col = pc ^ ((row & 7) << 4);
            *(s8v*)&resb[(size_t)(m0 + row) * CDIM + c0 + col] = *(const s8v*)&smem[idx];
        }
    } else {
        int h = (n0 - 2048) >> 7;
        int bb = m0 >> 9, lb = m0 & 511;
        #pragma unroll
        for (int i = 0; i < 8; ++i) {
            int idx = i * 2048 + t * 8;
            int d = idx >> 7, pr = idx & 127;
            int row = pr ^ ((d & 7) << 4);
            *(s8v*)&vt[(((size_t)bb * NH + h) * HD + d) * LDIM + lb + row] =
                *(const s8v*)&smem[idx];
        }
    }
#undef BOFF
}

// ---------------- Kernel 3: fused MFMA attention (round-8 version, kept) ------------
// Triple-bracketed at ~43us: L2-direct (worse, R4), dbuf pipeline (worse, R7),
// 4 blocks/CU occupancy (neutral, R8). Local structure floor; no counters visible
// (never in top-5) so further changes here are blind — frozen.
__global__ __launch_bounds__(256) void attn_kernel(const u16* __restrict__ ksig,
                                                   const u16* __restrict__ vt,
                                                   const u16* __restrict__ resb,
                                                   const u64* __restrict__ adjbits,
                                                   float* __restrict__ out) {
    __shared__ __align__(16) u16 lds_ks[64 * 128];  // swizzled: slot = row*16 + (seg^(row&15))
    __shared__ __align__(16) u16 lds_vt[128 * 64];  // swizzled: slot = row*8 + (seg^(row&7))
    __shared__ __align__(16) u16 lds_ps[4][16][64]; // per-wave P tile, XOR-swizzled cols

    int t = threadIdx.x;
    int lane = t & 63, w = t >> 6;
    int i15 = lane & 15, quad = lane >> 4;
    int bid = blockIdx.x;
    int l0 = (bid >> 7) * 64;
    int b  = (bid >> 3) & 15;
    int h  = bid & 7;

    const u16* ksig_bh = ksig + ((size_t)b * NH + h) * LDIM * HD;
    const u16* vt_bh   = vt + ((size_t)b * NH + h) * HD * LDIM;
    const u64* abits   = adjbits + ((size_t)b * LDIM + l0 + w * 16 + quad * 4) * (LDIM / 64);

    // Q A-frags from global (sigmoid pre-applied in GEMM epilogue)
    s8v aQ[4];
    {
        const u16* qrow = ksig_bh + (size_t)(l0 + w * 16 + i15) * HD + quad * 8;
        #pragma unroll
        for (int kc = 0; kc < 4; ++kc) aQ[kc] = *(const s8v*)(qrow + kc * 32);
    }

    f32x4 accO[8];
    #pragma unroll
    for (int i = 0; i < 8; ++i) accO[i] = (f32x4)(0.f);
    float prs[4] = {0.f, 0.f, 0.f, 0.f};

    const float scale = 0.08838834764831845f;  // 1/sqrt(128)

    for (int m0 = 0; m0 < LDIM; m0 += 64) {
        // --- stage K tile via DMA: 64 rows x 16 segs, 4 insts/thread ---
        #pragma unroll
        for (int p = 0; p < 4; ++p) {
            int sb = (w * 4 + p) * 64;
            int s = sb + lane;
            int row = s >> 4;
            int seg = (s & 15) ^ (row & 15);
            const u16* g = ksig_bh + (size_t)(m0 + row) * HD + seg * 8;
            __builtin_amdgcn_global_load_lds(
                (const __attribute__((address_space(1))) unsigned int*)g,
                (__attribute__((address_space(3))) unsigned int*)&lds_ks[sb * 8], 16, 0, 0);
        }
        // --- stage V^T tile via DMA: 128 rows x 8 segs, 4 insts/thread ---
        #pragma unroll
        for (int p = 0; p < 4; ++p) {
            int sb = (w * 4 + p) * 64;
            int s = sb + lane;
            int row = s >> 3;
            int seg = (s & 7) ^ (row & 7);
            const u16* g = vt_bh + (size_t)row * LDIM + m0 + seg * 8;
            __builtin_amdgcn_global_load_lds(
                (const __attribute__((address_space(1))) unsigned int*)g,
                (__attribute__((address_space(3))) unsigned int*)&lds_vt[sb * 8], 16, 0, 0);
        }
        // --- adj mask words for this m-chunk (broadcast loads, hide under DMA) ---
        unsigned int mw0[4], mw1[4];
        #pragma unroll
        for (int r = 0; r < 4; ++r) {
            u64 wrd = abits[(size_t)r * (LDIM / 64) + (m0 >> 6)];
            mw0[r] = (unsigned int)wrd;
            mw1[r] = (unsigned int)(wrd >> 32);
        }
        __syncthreads();

        // --- S = sig(Q) sig(K)^T : 4 key-tiles x 4 k-steps ---
        f32x4 S[4];
        #pragma unroll
        for (int nt = 0; nt < 4; ++nt) {
            S[nt] = (f32x4)(0.f);
            #pragma unroll
            for (int kc = 0; kc < 4; ++kc) {
                int row = nt * 16 + i15;
                int slot = row * 16 + ((kc * 4 + quad) ^ (row & 15));
                s8v bK = *(const s8v*)&lds_ks[slot * 8];
                S[nt] = __builtin_amdgcn_mfma_f32_16x16x32_bf16(aQ[kc], bK, S[nt], 0, 0, 0);
            }
        }

        // --- mask via bit-test, rowsum, P -> LDS (per-wave, no barrier) ---
        #pragma unroll
        for (int nt = 0; nt < 4; ++nt) {
            int sh = (nt & 1) * 16 + i15;
            int pcol = (nt * 16 + i15) ^ (quad << 4);
            #pragma unroll
            for (int r = 0; r < 4; ++r) {
                unsigned int half = (nt < 2) ? mw0[r] : mw1[r];
                float p = ((half >> sh) & 1u) ? S[nt][r] * scale : 0.f;
                prs[r] += p;
                lds_ps[w][quad * 4 + r][pcol] = f2bf(p);
            }
        }

        // --- O += P . V ---
        {
            s8v aP[2];
            #pragma unroll
            for (int ks = 0; ks < 2; ++ks)
                aP[ks] = *(const s8v*)&lds_ps[w][i15][(ks * 32 + quad * 8) ^ ((i15 >> 2) << 4)];
            #pragma unroll
            for (int ntd = 0; ntd < 8; ++ntd) {
                #pragma unroll
                for (int ks = 0; ks < 2; ++ks) {
                    int row = ntd * 16 + i15;
                    int slot = row * 8 + ((ks * 4 + quad) ^ (row & 7));
                    s8v bV = *(const s8v*)&lds_vt[slot * 8];
                    accO[ntd] = __builtin_amdgcn_mfma_f32_16x16x32_bf16(aP[ks], bV, accO[ntd], 0, 0, 0);
                }
            }
        }
        __syncthreads();
    }

    // --- epilogue: reduce rowsums across the 16 key-lanes, normalize, +res, relu ---
    float inv[4];
    #pragma unroll
    for (int r = 0; r < 4; ++r) {
        float s = prs[r];
        s += __shfl_xor(s, 1);
        s += __shfl_xor(s, 2);
        s += __shfl_xor(s, 4);
        s += __shfl_xor(s, 8);
        inv[r] = 1.0f / (s + 1e-6f);
    }
    #pragma unroll
    for (int ntd = 0; ntd < 8; ++ntd) {
        int dcol = h * HD + ntd * 16 + i15;
        #pragma unroll
        for (int r = 0; r < 4; ++r) {
            size_t idx = ((size_t)b * LDIM + l0 + w * 16 + quad * 4 + r) * CDIM + dcol;
            float v = accO[ntd][r] * inv[r] + bf2f(resb[idx]);
            out[idx] = fmaxf(v, 0.f);
        }
    }
}

// ---------------- launch ----------------
extern "C" void kernel_launch(void* const* d_in, const int* in_sizes, int n_in,
                              void* d_out, int out_size, void* d_ws, size_t ws_size,
                              hipStream_t stream) {
    (void)in_sizes; (void)n_in; (void)out_size; (void)ws_size;
    const float* x     = (const float*)d_in[0];
    const float* adj   = (const float*)d_in[1];
    const float* W_qkv = (const float*)d_in[2];
    const float* b_qkv = (const float*)d_in[3];
    const float* W_d   = (const float*)d_in[4];
    const float* b_d   = (const float*)d_in[5];
    float* out = (float*)d_out;

    char* ws = (char*)d_ws;
    size_t off = 0;
    u64* adjb   = (u64*)(ws + off);   off += (size_t)MROWS * 8 * 8;       // 512 KB
    u16*   xg   = (u16*)(ws + off);   off += (size_t)MROWS * CDIM * 2;    // 16 MB
    u16*   Wt   = (u16*)(ws + off);   off += (size_t)N3 * CDIM * 2;       // 6 MB
    u16*   ksig = (u16*)(ws + off);   off += (size_t)MROWS * CDIM * 2;    // 16 MB
    u16*   resb = (u16*)(ws + off);   off += (size_t)MROWS * CDIM * 2;    // 16 MB
    u16*   vt   = (u16*)(ws + off);   off += (size_t)MROWS * CDIM * 2;    // 16 MB

    prep_kernel<<<MROWS + (CDIM / 64) * (N3 / 64), 256, 0, stream>>>(
        adj, x, W_d, b_d, W_qkv, adjb, xg, Wt);
    gemm_bf16_kernel<<<dim3(N3 / 128, MROWS / 128), 256, 0, stream>>>(xg, Wt, b_qkv, ksig, resb, vt);
    attn_kernel<<<LDIM / 64 * NH * BDIM, 256, 0, stream>>>(ksig, vt, resb, adjb, out);
}

// Round 10
// 213.805 us; speedup vs baseline: 1.0120x; 1.0120x over previous
//
#include <hip/hip_runtime.h>
#include <math.h>

#define BDIM 16
#define LDIM 512
#define CDIM 1024
#define NH 8
#define HD 128
#define MROWS (BDIM * LDIM)   /* 8192 */
#define N3 (3 * CDIM)         /* 3072 */

typedef unsigned short u16;
typedef unsigned long long u64;
typedef short s8v __attribute__((ext_vector_type(8)));   // 8 bf16 = 4 VGPRs (MFMA A/B frag)
typedef short s4v __attribute__((ext_vector_type(4)));   // 4 bf16 = 2 VGPRs
typedef float f32x4 __attribute__((ext_vector_type(4))); // MFMA C/D frag

__device__ __forceinline__ float sigmoidf_(float z) {
    return 1.0f / (1.0f + __expf(-z));
}
__device__ __forceinline__ u16 f2bf(float f) {
    union { float f; unsigned int u; } v; v.f = f;
    unsigned int u = v.u;
    unsigned int r = (u + 0x7FFFu + ((u >> 16) & 1u)) >> 16;   // round-nearest-even
    return (u16)r;
}
__device__ __forceinline__ float bf2f(u16 b) {
    union { unsigned int u; float f; } v; v.u = ((unsigned int)b) << 16;
    return v.f;
}

// ---------------- Kernel 1: fused prep ----------------
// blocks [0, MROWS):       row r -> degree (block reduce) + adj bitmask pack + gate
// blocks [MROWS, +768):    packW tile: Wt[n][k] = bf16(W[k][n])
__global__ __launch_bounds__(256) void prep_kernel(const float* __restrict__ adj,
                                                   const float* __restrict__ x,
                                                   const float* __restrict__ Wd,
                                                   const float* __restrict__ bd,
                                                   const float* __restrict__ W,
                                                   u64* __restrict__ adjbits,
                                                   u16* __restrict__ xg,
                                                   u16* __restrict__ Wt) {
    __shared__ float tile[64][65];   // packW transpose tile; prep path uses tile[0][0..3]
    int bid = blockIdx.x;
    int t = threadIdx.x;
    if (bid < MROWS) {
        int row = bid;
        int lane = t & 63, w = t >> 6;
        const float* a = adj + (size_t)row * LDIM;
        float s = 0.f;
        #pragma unroll
        for (int j = 0; j < 2; ++j) {
            int mc = j * 256 + w * 64;              // word index mc>>6 = j*4 + w
            float v = a[mc + lane];
            s += v;
            u64 m = __ballot(v != 0.f);
            if (lane == 0) adjbits[(size_t)row * (LDIM / 64) + (mc >> 6)] = m;
        }
        #pragma unroll
        for (int off = 32; off > 0; off >>= 1) s += __shfl_down(s, off);
        if (lane == 0) tile[0][w] = s;
        __syncthreads();
        float d = tile[0][0] + tile[0][1] + tile[0][2] + tile[0][3];
        float4 xv = ((const float4*)(x + (size_t)row * CDIM))[t];
        float4 wv = ((const float4*)Wd)[t];
        float4 bv = ((const float4*)bd)[t];
        s4v o;
        o.x = (short)f2bf(xv.x * sigmoidf_(d * wv.x + bv.x));
        o.y = (short)f2bf(xv.y * sigmoidf_(d * wv.y + bv.y));
        o.z = (short)f2bf(xv.z * sigmoidf_(d * wv.z + bv.z));
        o.w = (short)f2bf(xv.w * sigmoidf_(d * wv.w + bv.w));
        ((s4v*)(xg + (size_t)row * CDIM))[t] = o;
    } else {
        int pb = bid - MROWS;
        int k0 = (pb & 15) * 64, n0 = (pb >> 4) * 64;
        int tx = t & 63, ty = t >> 6;  // ty 0..3
        #pragma unroll
        for (int yy = ty; yy < 64; yy += 4)
            tile[yy][tx] = W[(size_t)(k0 + yy) * N3 + n0 + tx];
        __syncthreads();
        #pragma unroll
        for (int yy = ty; yy < 64; yy += 4)
            Wt[(size_t)(n0 + yy) * CDIM + k0 + tx] = f2bf(tile[tx][yy]);
    }
}

// ---------------- Kernel 2: bf16 MFMA GEMM (m97-style), LDS-coalesced epilogue ------
// K-loop = round-0 structure (8-phase falsified 3x). R9 epilogue: WRITE_SIZE 72->48MB
// (coalesced LDS flush) but dur ~neutral -> stores were hidden; kept for -23MB HBM.
// ROUND-10 CHANGE (one variable): __launch_bounds__(256,3) -> (256,4).
// Resources permit 4 blocks/CU (VGPR 64 + AGPR 64 = 128 = exactly the 4-waves/SIMD
// boundary; LDS 32KB = 5-block limit) yet OccupancyPercent ~29% (~2.3 blocks avg).
// More co-resident blocks = uncorrelated barrier drains = the TLP that hides this
// kernel's per-iter vmcnt(0) stall. Must NOT spill (watch VGPR_Count/scratch).
__global__ __launch_bounds__(256, 4) void gemm_bf16_kernel(const u16* __restrict__ A,
                                                           const u16* __restrict__ Bt,
                                                           const float* __restrict__ bias,
                                                           u16* __restrict__ ksig,
                                                           u16* __restrict__ resb,
                                                           u16* __restrict__ vt) {
    __shared__ __align__(16) u16 smem[128 * 128];  // K-loop: A=[0,8192) B=[8192,16384); epilogue: C-tile
#define BOFF (128 * 64)
    int t = threadIdx.x;
    int m0 = blockIdx.y * 128, n0 = blockIdx.x * 128;
    int lane = t & 63, w = t >> 6;
    int i15 = lane & 15, quad = lane >> 4;
    int wm = w >> 1, wn = w & 1;

    f32x4 acc[4][4];
    #pragma unroll
    for (int i = 0; i < 4; ++i)
        #pragma unroll
        for (int j = 0; j < 4; ++j) acc[i][j] = (f32x4)(0.f);

    for (int k0 = 0; k0 < CDIM; k0 += 64) {
        #pragma unroll
        for (int p = 0; p < 4; ++p) {
            int sb = (w * 4 + p) * 64;           // wave-uniform slot base
            int s = sb + lane;
            int row = s >> 3;
            int seg = (s & 7) ^ (row & 7);       // global-side XOR swizzle
            const u16* ga = A + (size_t)(m0 + row) * CDIM + k0 + seg * 8;
            const u16* gb = Bt + (size_t)(n0 + row) * CDIM + k0 + seg * 8;
            __builtin_amdgcn_global_load_lds(
                (const __attribute__((address_space(1))) unsigned int*)ga,
                (__attribute__((address_space(3))) unsigned int*)&smem[sb * 8], 16, 0, 0);
            __builtin_amdgcn_global_load_lds(
                (const __attribute__((address_space(1))) unsigned int*)gb,
                (__attribute__((address_space(3))) unsigned int*)&smem[BOFF + sb * 8], 16, 0, 0);
        }
        __syncthreads();
        #pragma unroll
        for (int kc = 0; kc < 2; ++kc) {
            s8v aF[4], bF[4];
            #pragma unroll
            for (int mt = 0; mt < 4; ++mt) {
                int row = wm * 64 + mt * 16 + i15;
                int slot = row * 8 + ((kc * 4 + quad) ^ (i15 & 7));
                aF[mt] = *(const s8v*)&smem[slot * 8];
            }
            #pragma unroll
            for (int nt = 0; nt < 4; ++nt) {
                int row = wn * 64 + nt * 16 + i15;
                int slot = row * 8 + ((kc * 4 + quad) ^ (i15 & 7));
                bF[nt] = *(const s8v*)&smem[BOFF + slot * 8];
            }
            #pragma unroll
            for (int mt = 0; mt < 4; ++mt)
                #pragma unroll
                for (int nt = 0; nt < 4; ++nt)
                    acc[mt][nt] = __builtin_amdgcn_mfma_f32_16x16x32_bf16(aF[mt], bF[nt], acc[mt][nt], 0, 0, 0);
        }
        __syncthreads();   // last iteration: all As/Bs reads retired -> smem reusable
    }

    int chunk = n0 >> 10;
    // ---- pack acc -> LDS C-tile (swizzled; transposed for chunk 2) ----
    #pragma unroll
    for (int nt = 0; nt < 4; ++nt) {
        int lcol = wn * 64 + nt * 16 + i15;          // 0..127 within tile
        float bv = bias[n0 + lcol];
        #pragma unroll
        for (int mt = 0; mt < 4; ++mt) {
            int lrow0 = wm * 64 + mt * 16 + quad * 4;
            #pragma unroll
            for (int r = 0; r < 4; ++r) {
                int lrow = lrow0 + r;
                float v = acc[mt][nt][r] + bv;
                if (chunk == 0) v = sigmoidf_(v);
                u16 bf = f2bf(v);
                if (chunk == 2)
                    smem[lcol * 128 + (lrow ^ ((lcol & 7) << 4))] = bf;   // [d][l]
                else
                    smem[lrow * 128 + (lcol ^ ((lrow & 7) << 4))] = bf;   // [row][col]
            }
        }
    }
    __syncthreads();
    // ---- coalesced flush: 8 x 16B per thread ----
    if (chunk == 0) {
        int h = (n0 >> 7) & 7;
        int bb = m0 >> 9, lb = m0 & 511;
        #pragma unroll
        for (int i = 0; i < 8; ++i) {
            int idx = i * 2048 + t * 8;              // u16 units
            int row = idx >> 7, pc = idx & 127;
            int col = pc ^ ((row & 7) << 4);
            *(s8v*)&ksig[(((size_t)bb * NH + h) * LDIM + lb + row) * HD + col] =
                *(const s8v*)&smem[idx];
        }
    } else if (chunk == 1) {
        int c0 = n0 - CDIM;
        #pragma unroll
        for (int i = 0; i < 8; ++i) {
            int idx = i * 2048 + t * 8;
            int row = idx >> 7, pc = idx & 127;
            int col = pc ^ ((row & 7) << 4);
            *(s8v*)&resb[(size_t)(m0 + row) * CDIM + c0 + col] = *(const s8v*)&smem[idx];
        }
    } else {
        int h = (n0 - 2048) >> 7;
        int bb = m0 >> 9, lb = m0 & 511;
        #pragma unroll
        for (int i = 0; i < 8; ++i) {
            int idx = i * 2048 + t * 8;
            int d = idx >> 7, pr = idx & 127;
            int row = pr ^ ((d & 7) << 4);
            *(s8v*)&vt[(((size_t)bb * NH + h) * HD + d) * LDIM + lb + row] =
                *(const s8v*)&smem[idx];
        }
    }
#undef BOFF
}

// ---------------- Kernel 3: fused MFMA attention (round-8 version, frozen) ----------
// Triple-bracketed at ~43us: L2-direct (worse, R4), dbuf pipeline (worse, R7),
// 4 blocks/CU occupancy (neutral, R8). Local structure floor; no counters visible
// (never in top-5) so further changes here are blind.
__global__ __launch_bounds__(256) void attn_kernel(const u16* __restrict__ ksig,
                                                   const u16* __restrict__ vt,
                                                   const u16* __restrict__ resb,
                                                   const u64* __restrict__ adjbits,
                                                   float* __restrict__ out) {
    __shared__ __align__(16) u16 lds_ks[64 * 128];  // swizzled: slot = row*16 + (seg^(row&15))
    __shared__ __align__(16) u16 lds_vt[128 * 64];  // swizzled: slot = row*8 + (seg^(row&7))
    __shared__ __align__(16) u16 lds_ps[4][16][64]; // per-wave P tile, XOR-swizzled cols

    int t = threadIdx.x;
    int lane = t & 63, w = t >> 6;
    int i15 = lane & 15, quad = lane >> 4;
    int bid = blockIdx.x;
    int l0 = (bid >> 7) * 64;
    int b  = (bid >> 3) & 15;
    int h  = bid & 7;

    const u16* ksig_bh = ksig + ((size_t)b * NH + h) * LDIM * HD;
    const u16* vt_bh   = vt + ((size_t)b * NH + h) * HD * LDIM;
    const u64* abits   = adjbits + ((size_t)b * LDIM + l0 + w * 16 + quad * 4) * (LDIM / 64);

    // Q A-frags from global (sigmoid pre-applied in GEMM epilogue)
    s8v aQ[4];
    {
        const u16* qrow = ksig_bh + (size_t)(l0 + w * 16 + i15) * HD + quad * 8;
        #pragma unroll
        for (int kc = 0; kc < 4; ++kc) aQ[kc] = *(const s8v*)(qrow + kc * 32);
    }

    f32x4 accO[8];
    #pragma unroll
    for (int i = 0; i < 8; ++i) accO[i] = (f32x4)(0.f);
    float prs[4] = {0.f, 0.f, 0.f, 0.f};

    const float scale = 0.08838834764831845f;  // 1/sqrt(128)

    for (int m0 = 0; m0 < LDIM; m0 += 64) {
        // --- stage K tile via DMA: 64 rows x 16 segs, 4 insts/thread ---
        #pragma unroll
        for (int p = 0; p < 4; ++p) {
            int sb = (w * 4 + p) * 64;
            int s = sb + lane;
            int row = s >> 4;
            int seg = (s & 15) ^ (row & 15);
            const u16* g = ksig_bh + (size_t)(m0 + row) * HD + seg * 8;
            __builtin_amdgcn_global_load_lds(
                (const __attribute__((address_space(1))) unsigned int*)g,
                (__attribute__((address_space(3))) unsigned int*)&lds_ks[sb * 8], 16, 0, 0);
        }
        // --- stage V^T tile via DMA: 128 rows x 8 segs, 4 insts/thread ---
        #pragma unroll
        for (int p = 0; p < 4; ++p) {
            int sb = (w * 4 + p) * 64;
            int s = sb + lane;
            int row = s >> 3;
            int seg = (s & 7) ^ (row & 7);
            const u16* g = vt_bh + (size_t)row * LDIM + m0 + seg * 8;
            __builtin_amdgcn_global_load_lds(
                (const __attribute__((address_space(1))) unsigned int*)g,
                (__attribute__((address_space(3))) unsigned int*)&lds_vt[sb * 8], 16, 0, 0);
        }
        // --- adj mask words for this m-chunk (broadcast loads, hide under DMA) ---
        unsigned int mw0[4], mw1[4];
        #pragma unroll
        for (int r = 0; r < 4; ++r) {
            u64 wrd = abits[(size_t)r * (LDIM / 64) + (m0 >> 6)];
            mw0[r] = (unsigned int)wrd;
            mw1[r] = (unsigned int)(wrd >> 32);
        }
        __syncthreads();

        // --- S = sig(Q) sig(K)^T : 4 key-tiles x 4 k-steps ---
        f32x4 S[4];
        #pragma unroll
        for (int nt = 0; nt < 4; ++nt) {
            S[nt] = (f32x4)(0.f);
            #pragma unroll
            for (int kc = 0; kc < 4; ++kc) {
                int row = nt * 16 + i15;
                int slot = row * 16 + ((kc * 4 + quad) ^ (row & 15));
                s8v bK = *(const s8v*)&lds_ks[slot * 8];
                S[nt] = __builtin_amdgcn_mfma_f32_16x16x32_bf16(aQ[kc], bK, S[nt], 0, 0, 0);
            }
        }

        // --- mask via bit-test, rowsum, P -> LDS (per-wave, no barrier) ---
        #pragma unroll
        for (int nt = 0; nt < 4; ++nt) {
            int sh = (nt & 1) * 16 + i15;
            int pcol = (nt * 16 + i15) ^ (quad << 4);
            #pragma unroll
            for (int r = 0; r < 4; ++r) {
                unsigned int half = (nt < 2) ? mw0[r] : mw1[r];
                float p = ((half >> sh) & 1u) ? S[nt][r] * scale : 0.f;
                prs[r] += p;
                lds_ps[w][quad * 4 + r][pcol] = f2bf(p);
            }
        }

        // --- O += P . V ---
        {
            s8v aP[2];
            #pragma unroll
            for (int ks = 0; ks < 2; ++ks)
                aP[ks] = *(const s8v*)&lds_ps[w][i15][(ks * 32 + quad * 8) ^ ((i15 >> 2) << 4)];
            #pragma unroll
            for (int ntd = 0; ntd < 8; ++ntd) {
                #pragma unroll
                for (int ks = 0; ks < 2; ++ks) {
                    int row = ntd * 16 + i15;
                    int slot = row * 8 + ((ks * 4 + quad) ^ (row & 7));
                    s8v bV = *(const s8v*)&lds_vt[slot * 8];
                    accO[ntd] = __builtin_amdgcn_mfma_f32_16x16x32_bf16(aP[ks], bV, accO[ntd], 0, 0, 0);
                }
            }
        }
        __syncthreads();
    }

    // --- epilogue: reduce rowsums across the 16 key-lanes, normalize, +res, relu ---
    float inv[4];
    #pragma unroll
    for (int r = 0; r < 4; ++r) {
        float s = prs[r];
        s += __shfl_xor(s, 1);
        s += __shfl_xor(s, 2);
        s += __shfl_xor(s, 4);
        s += __shfl_xor(s, 8);
        inv[r] = 1.0f / (s + 1e-6f);
    }
    #pragma unroll
    for (int ntd = 0; ntd < 8; ++ntd) {
        int dcol = h * HD + ntd * 16 + i15;
        #pragma unroll
        for (int r = 0; r < 4; ++r) {
            size_t idx = ((size_t)b * LDIM + l0 + w * 16 + quad * 4 + r) * CDIM + dcol;
            float v = accO[ntd][r] * inv[r] + bf2f(resb[idx]);
            out[idx] = fmaxf(v, 0.f);
        }
    }
}

// ---------------- launch ----------------
extern "C" void kernel_launch(void* const* d_in, const int* in_sizes, int n_in,
                              void* d_out, int out_size, void* d_ws, size_t ws_size,
                              hipStream_t stream) {
    (void)in_sizes; (void)n_in; (void)out_size; (void)ws_size;
    const float* x     = (const float*)d_in[0];
    const float* adj   = (const float*)d_in[1];
    const float* W_qkv = (const float*)d_in[2];
    const float* b_qkv = (const float*)d_in[3];
    const float* W_d   = (const float*)d_in[4];
    const float* b_d   = (const float*)d_in[5];
    float* out = (float*)d_out;

    char* ws = (char*)d_ws;
    size_t off = 0;
    u64* adjb   = (u64*)(ws + off);   off += (size_t)MROWS * 8 * 8;       // 512 KB
    u16*   xg   = (u16*)(ws + off);   off += (size_t)MROWS * CDIM * 2;    // 16 MB
    u16*   Wt   = (u16*)(ws + off);   off += (size_t)N3 * CDIM * 2;       // 6 MB
    u16*   ksig = (u16*)(ws + off);   off += (size_t)MROWS * CDIM * 2;    // 16 MB
    u16*   resb = (u16*)(ws + off);   off += (size_t)MROWS * CDIM * 2;    // 16 MB
    u16*   vt   = (u16*)(ws + off);   off += (size_t)MROWS * CDIM * 2;    // 16 MB

    prep_kernel<<<MROWS + (CDIM / 64) * (N3 / 64), 256, 0, stream>>>(
        adj, x, W_d, b_d, W_qkv, adjb, xg, Wt);
    gemm_bf16_kernel<<<dim3(N3 / 128, MROWS / 128), 256, 0, stream>>>(xg, Wt, b_qkv, ksig, resb, vt);
    attn_kernel<<<LDIM / 64 * NH * BDIM, 256, 0, stream>>>(ksig, vt, resb, adjb, out);
}

// Round 11
// 210.477 us; speedup vs baseline: 1.0280x; 1.0158x over previous
//
#include <hip/hip_runtime.h>
#include <math.h>

#define BDIM 16
#define LDIM 512
#define CDIM 1024
#define NH 8
#define HD 128
#define MROWS (BDIM * LDIM)   /* 8192 */
#define N3 (3 * CDIM)         /* 3072 */

typedef unsigned short u16;
typedef unsigned long long u64;
typedef short s8v __attribute__((ext_vector_type(8)));   // 8 bf16 = 4 VGPRs (MFMA A/B frag)
typedef short s4v __attribute__((ext_vector_type(4)));   // 4 bf16 = 2 VGPRs
typedef float f32x4 __attribute__((ext_vector_type(4))); // MFMA C/D frag

__device__ __forceinline__ float sigmoidf_(float z) {
    return 1.0f / (1.0f + __expf(-z));
}
__device__ __forceinline__ u16 f2bf(float f) {
    union { float f; unsigned int u; } v; v.f = f;
    unsigned int u = v.u;
    unsigned int r = (u + 0x7FFFu + ((u >> 16) & 1u)) >> 16;   // round-nearest-even
    return (u16)r;
}
__device__ __forceinline__ float bf2f(u16 b) {
    union { unsigned int u; float f; } v; v.u = ((unsigned int)b) << 16;
    return v.f;
}

// ---------------- Kernel 1: fused prep ----------------
// blocks [0, MROWS):       row r -> degree (block reduce) + adj bitmask pack + gate
// blocks [MROWS, +768):    packW tile: Wt[n][k] = bf16(W[k][n])
__global__ __launch_bounds__(256) void prep_kernel(const float* __restrict__ adj,
                                                   const float* __restrict__ x,
                                                   const float* __restrict__ Wd,
                                                   const float* __restrict__ bd,
                                                   const float* __restrict__ W,
                                                   u64* __restrict__ adjbits,
                                                   u16* __restrict__ xg,
                                                   u16* __restrict__ Wt) {
    __shared__ float tile[64][65];   // packW transpose tile; prep path uses tile[0][0..3]
    int bid = blockIdx.x;
    int t = threadIdx.x;
    if (bid < MROWS) {
        int row = bid;
        int lane = t & 63, w = t >> 6;
        const float* a = adj + (size_t)row * LDIM;
        float s = 0.f;
        #pragma unroll
        for (int j = 0; j < 2; ++j) {
            int mc = j * 256 + w * 64;              // word index mc>>6 = j*4 + w
            float v = a[mc + lane];
            s += v;
            u64 m = __ballot(v != 0.f);
            if (lane == 0) adjbits[(size_t)row * (LDIM / 64) + (mc >> 6)] = m;
        }
        #pragma unroll
        for (int off = 32; off > 0; off >>= 1) s += __shfl_down(s, off);
        if (lane == 0) tile[0][w] = s;
        __syncthreads();
        float d = tile[0][0] + tile[0][1] + tile[0][2] + tile[0][3];
        float4 xv = ((const float4*)(x + (size_t)row * CDIM))[t];
        float4 wv = ((const float4*)Wd)[t];
        float4 bv = ((const float4*)bd)[t];
        s4v o;
        o.x = (short)f2bf(xv.x * sigmoidf_(d * wv.x + bv.x));
        o.y = (short)f2bf(xv.y * sigmoidf_(d * wv.y + bv.y));
        o.z = (short)f2bf(xv.z * sigmoidf_(d * wv.z + bv.z));
        o.w = (short)f2bf(xv.w * sigmoidf_(d * wv.w + bv.w));
        ((s4v*)(xg + (size_t)row * CDIM))[t] = o;
    } else {
        int pb = bid - MROWS;
        int k0 = (pb & 15) * 64, n0 = (pb >> 4) * 64;
        int tx = t & 63, ty = t >> 6;  // ty 0..3
        #pragma unroll
        for (int yy = ty; yy < 64; yy += 4)
            tile[yy][tx] = W[(size_t)(k0 + yy) * N3 + n0 + tx];
        __syncthreads();
        #pragma unroll
        for (int yy = ty; yy < 64; yy += 4)
            Wt[(size_t)(n0 + yy) * CDIM + k0 + tx] = f2bf(tile[tx][yy]);
    }
}

// ---------------- Kernel 2: bf16 MFMA GEMM (m97-style), LDS-coalesced epilogue ------
// Structural floor for this family (R1-R3: 8-phase falsified; R9: write-coalescing
// counter-confirmed but hidden; R10: occupancy hint neutral). Frozen.
__global__ __launch_bounds__(256, 4) void gemm_bf16_kernel(const u16* __restrict__ A,
                                                           const u16* __restrict__ Bt,
                                                           const float* __restrict__ bias,
                                                           u16* __restrict__ ksig,
                                                           u16* __restrict__ resb,
                                                           u16* __restrict__ vt) {
    __shared__ __align__(16) u16 smem[128 * 128];  // K-loop: A=[0,8192) B=[8192,16384); epilogue: C-tile
#define BOFF (128 * 64)
    int t = threadIdx.x;
    int m0 = blockIdx.y * 128, n0 = blockIdx.x * 128;
    int lane = t & 63, w = t >> 6;
    int i15 = lane & 15, quad = lane >> 4;
    int wm = w >> 1, wn = w & 1;

    f32x4 acc[4][4];
    #pragma unroll
    for (int i = 0; i < 4; ++i)
        #pragma unroll
        for (int j = 0; j < 4; ++j) acc[i][j] = (f32x4)(0.f);

    for (int k0 = 0; k0 < CDIM; k0 += 64) {
        #pragma unroll
        for (int p = 0; p < 4; ++p) {
            int sb = (w * 4 + p) * 64;           // wave-uniform slot base
            int s = sb + lane;
            int row = s >> 3;
            int seg = (s & 7) ^ (row & 7);       // global-side XOR swizzle
            const u16* ga = A + (size_t)(m0 + row) * CDIM + k0 + seg * 8;
            const u16* gb = Bt + (size_t)(n0 + row) * CDIM + k0 + seg * 8;
            __builtin_amdgcn_global_load_lds(
                (const __attribute__((address_space(1))) unsigned int*)ga,
                (__attribute__((address_space(3))) unsigned int*)&smem[sb * 8], 16, 0, 0);
            __builtin_amdgcn_global_load_lds(
                (const __attribute__((address_space(1))) unsigned int*)gb,
                (__attribute__((address_space(3))) unsigned int*)&smem[BOFF + sb * 8], 16, 0, 0);
        }
        __syncthreads();
        #pragma unroll
        for (int kc = 0; kc < 2; ++kc) {
            s8v aF[4], bF[4];
            #pragma unroll
            for (int mt = 0; mt < 4; ++mt) {
                int row = wm * 64 + mt * 16 + i15;
                int slot = row * 8 + ((kc * 4 + quad) ^ (i15 & 7));
                aF[mt] = *(const s8v*)&smem[slot * 8];
            }
            #pragma unroll
            for (int nt = 0; nt < 4; ++nt) {
                int row = wn * 64 + nt * 16 + i15;
                int slot = row * 8 + ((kc * 4 + quad) ^ (i15 & 7));
                bF[nt] = *(const s8v*)&smem[BOFF + slot * 8];
            }
            #pragma unroll
            for (int mt = 0; mt < 4; ++mt)
                #pragma unroll
                for (int nt = 0; nt < 4; ++nt)
                    acc[mt][nt] = __builtin_amdgcn_mfma_f32_16x16x32_bf16(aF[mt], bF[nt], acc[mt][nt], 0, 0, 0);
        }
        __syncthreads();   // last iteration: all As/Bs reads retired -> smem reusable
    }

    int chunk = n0 >> 10;
    // ---- pack acc -> LDS C-tile (swizzled; transposed for chunk 2) ----
    #pragma unroll
    for (int nt = 0; nt < 4; ++nt) {
        int lcol = wn * 64 + nt * 16 + i15;          // 0..127 within tile
        float bv = bias[n0 + lcol];
        #pragma unroll
        for (int mt = 0; mt < 4; ++mt) {
            int lrow0 = wm * 64 + mt * 16 + quad * 4;
            #pragma unroll
            for (int r = 0; r < 4; ++r) {
                int lrow = lrow0 + r;
                float v = acc[mt][nt][r] + bv;
                if (chunk == 0) v = sigmoidf_(v);
                u16 bf = f2bf(v);
                if (chunk == 2)
                    smem[lcol * 128 + (lrow ^ ((lcol & 7) << 4))] = bf;   // [d][l]
                else
                    smem[lrow * 128 + (lcol ^ ((lrow & 7) << 4))] = bf;   // [row][col]
            }
        }
    }
    __syncthreads();
    // ---- coalesced flush: 8 x 16B per thread ----
    if (chunk == 0) {
        int h = (n0 >> 7) & 7;
        int bb = m0 >> 9, lb = m0 & 511;
        #pragma unroll
        for (int i = 0; i < 8; ++i) {
            int idx = i * 2048 + t * 8;              // u16 units
            int row = idx >> 7, pc = idx & 127;
            int col = pc ^ ((row & 7) << 4);
            *(s8v*)&ksig[(((size_t)bb * NH + h) * LDIM + lb + row) * HD + col] =
                *(const s8v*)&smem[idx];
        }
    } else if (chunk == 1) {
        int c0 = n0 - CDIM;
        #pragma unroll
        for (int i = 0; i < 8; ++i) {
            int idx = i * 2048 + t * 8;
            int row = idx >> 7, pc = idx & 127;
            int col = pc ^ ((row & 7) << 4);
            *(s8v*)&resb[(size_t)(m0 + row) * CDIM + c0 + col] = *(const s8v*)&smem[idx];
        }
    } else {
        int h = (n0 - 2048) >> 7;
        int bb = m0 >> 9, lb = m0 & 511;
        #pragma unroll
        for (int i = 0; i < 8; ++i) {
            int idx = i * 2048 + t * 8;
            int d = idx >> 7, pr = idx & 127;
            int row = pr ^ ((d & 7) << 4);
            *(s8v*)&vt[(((size_t)bb * NH + h) * HD + d) * LDIM + lb + row] =
                *(const s8v*)&smem[idx];
        }
    }
#undef BOFF
}

// ---------------- Kernel 3: fused MFMA attention, 2 l-tiles per block ---------------
// ROUND-11 CHANGE (work reduction, final experiment): 8 l-tiles of each (b,h) all
// staged the SAME K/V tiles (1024 blocks x 256KB = 262MB staged). Pair l0 and l0+256
// into one block: 512 blocks, staged traffic and DMA issue HALVED, MFMA per barrier
// DOUBLED (stall amortization 2x). Per-tile math byte-identical to the verified
// version, duplicated (aQ/acc/prs/mask x2). lds_ps reused per-wave sequentially
// between tiles (within-wave lgkmcnt ordering; no extra barriers). VGPR ~56+50;
// even at 3 blocks/CU, 512 blocks still fit in one dispatch round.
__global__ __launch_bounds__(256) void attn_kernel(const u16* __restrict__ ksig,
                                                   const u16* __restrict__ vt,
                                                   const u16* __restrict__ resb,
                                                   const u64* __restrict__ adjbits,
                                                   float* __restrict__ out) {
    __shared__ __align__(16) u16 lds_ks[64 * 128];  // swizzled: slot = row*16 + (seg^(row&15))
    __shared__ __align__(16) u16 lds_vt[128 * 64];  // swizzled: slot = row*8 + (seg^(row&7))
    __shared__ __align__(16) u16 lds_ps[4][16][64]; // per-wave P tile, XOR-swizzled cols

    int t = threadIdx.x;
    int lane = t & 63, w = t >> 6;
    int i15 = lane & 15, quad = lane >> 4;
    int bid = blockIdx.x;                // 512 blocks: bid>>7 in 0..3
    int l0a = (bid >> 7) * 64;
    int l0b = l0a + 256;
    int b  = (bid >> 3) & 15;
    int h  = bid & 7;

    const u16* ksig_bh = ksig + ((size_t)b * NH + h) * LDIM * HD;
    const u16* vt_bh   = vt + ((size_t)b * NH + h) * HD * LDIM;
    const u64* abA = adjbits + ((size_t)b * LDIM + l0a + w * 16 + quad * 4) * (LDIM / 64);
    const u64* abB = adjbits + ((size_t)b * LDIM + l0b + w * 16 + quad * 4) * (LDIM / 64);

    // Q A-frags for both l-tiles (sigmoid pre-applied in GEMM epilogue)
    s8v aQa[4], aQb[4];
    {
        const u16* qA = ksig_bh + (size_t)(l0a + w * 16 + i15) * HD + quad * 8;
        const u16* qB = ksig_bh + (size_t)(l0b + w * 16 + i15) * HD + quad * 8;
        #pragma unroll
        for (int kc = 0; kc < 4; ++kc) {
            aQa[kc] = *(const s8v*)(qA + kc * 32);
            aQb[kc] = *(const s8v*)(qB + kc * 32);
        }
    }

    f32x4 accA[8], accB[8];
    #pragma unroll
    for (int i = 0; i < 8; ++i) { accA[i] = (f32x4)(0.f); accB[i] = (f32x4)(0.f); }
    float prsA[4] = {0.f, 0.f, 0.f, 0.f};
    float prsB[4] = {0.f, 0.f, 0.f, 0.f};

    const float scale = 0.08838834764831845f;  // 1/sqrt(128)

    for (int m0 = 0; m0 < LDIM; m0 += 64) {
        // --- stage K tile via DMA: 64 rows x 16 segs, 4 insts/thread ---
        #pragma unroll
        for (int p = 0; p < 4; ++p) {
            int sb = (w * 4 + p) * 64;
            int s = sb + lane;
            int row = s >> 4;
            int seg = (s & 15) ^ (row & 15);
            const u16* g = ksig_bh + (size_t)(m0 + row) * HD + seg * 8;
            __builtin_amdgcn_global_load_lds(
                (const __attribute__((address_space(1))) unsigned int*)g,
                (__attribute__((address_space(3))) unsigned int*)&lds_ks[sb * 8], 16, 0, 0);
        }
        // --- stage V^T tile via DMA: 128 rows x 8 segs, 4 insts/thread ---
        #pragma unroll
        for (int p = 0; p < 4; ++p) {
            int sb = (w * 4 + p) * 64;
            int s = sb + lane;
            int row = s >> 3;
            int seg = (s & 7) ^ (row & 7);
            const u16* g = vt_bh + (size_t)row * LDIM + m0 + seg * 8;
            __builtin_amdgcn_global_load_lds(
                (const __attribute__((address_space(1))) unsigned int*)g,
                (__attribute__((address_space(3))) unsigned int*)&lds_vt[sb * 8], 16, 0, 0);
        }
        // --- adj mask words for both l-tiles (broadcast loads, hide under DMA) ---
        unsigned int mwA0[4], mwA1[4], mwB0[4], mwB1[4];
        #pragma unroll
        for (int r = 0; r < 4; ++r) {
            u64 wa = abA[(size_t)r * (LDIM / 64) + (m0 >> 6)];
            u64 wb = abB[(size_t)r * (LDIM / 64) + (m0 >> 6)];
            mwA0[r] = (unsigned int)wa; mwA1[r] = (unsigned int)(wa >> 32);
            mwB0[r] = (unsigned int)wb; mwB1[r] = (unsigned int)(wb >> 32);
        }
        __syncthreads();

        // ================= tile A =================
        {
            f32x4 S[4];
            #pragma unroll
            for (int nt = 0; nt < 4; ++nt) {
                S[nt] = (f32x4)(0.f);
                #pragma unroll
                for (int kc = 0; kc < 4; ++kc) {
                    int row = nt * 16 + i15;
                    int slot = row * 16 + ((kc * 4 + quad) ^ (row & 15));
                    s8v bK = *(const s8v*)&lds_ks[slot * 8];
                    S[nt] = __builtin_amdgcn_mfma_f32_16x16x32_bf16(aQa[kc], bK, S[nt], 0, 0, 0);
                }
            }
            #pragma unroll
            for (int nt = 0; nt < 4; ++nt) {
                int sh = (nt & 1) * 16 + i15;
                int pcol = (nt * 16 + i15) ^ (quad << 4);
                #pragma unroll
                for (int r = 0; r < 4; ++r) {
                    unsigned int half = (nt < 2) ? mwA0[r] : mwA1[r];
                    float p = ((half >> sh) & 1u) ? S[nt][r] * scale : 0.f;
                    prsA[r] += p;
                    lds_ps[w][quad * 4 + r][pcol] = f2bf(p);
                }
            }
            s8v aP[2];
            #pragma unroll
            for (int ks = 0; ks < 2; ++ks)
                aP[ks] = *(const s8v*)&lds_ps[w][i15][(ks * 32 + quad * 8) ^ ((i15 >> 2) << 4)];
            #pragma unroll
            for (int ntd = 0; ntd < 8; ++ntd) {
                #pragma unroll
                for (int ks = 0; ks < 2; ++ks) {
                    int row = ntd * 16 + i15;
                    int slot = row * 8 + ((ks * 4 + quad) ^ (row & 7));
                    s8v bV = *(const s8v*)&lds_vt[slot * 8];
                    accA[ntd] = __builtin_amdgcn_mfma_f32_16x16x32_bf16(aP[ks], bV, accA[ntd], 0, 0, 0);
                }
            }
        }
        // ================= tile B (lds_ps reuse: within-wave sequential) =================
        {
            f32x4 S[4];
            #pragma unroll
            for (int nt = 0; nt < 4; ++nt) {
                S[nt] = (f32x4)(0.f);
                #pragma unroll
                for (int kc = 0; kc < 4; ++kc) {
                    int row = nt * 16 + i15;
                    int slot = row * 16 + ((kc * 4 + quad) ^ (row & 15));
                    s8v bK = *(const s8v*)&lds_ks[slot * 8];
                    S[nt] = __builtin_amdgcn_mfma_f32_16x16x32_bf16(aQb[kc], bK, S[nt], 0, 0, 0);
                }
            }
            #pragma unroll
            for (int nt = 0; nt < 4; ++nt) {
                int sh = (nt & 1) * 16 + i15;
                int pcol = (nt * 16 + i15) ^ (quad << 4);
                #pragma unroll
                for (int r = 0; r < 4; ++r) {
                    unsigned int half = (nt < 2) ? mwB0[r] : mwB1[r];
                    float p = ((half >> sh) & 1u) ? S[nt][r] * scale : 0.f;
                    prsB[r] += p;
                    lds_ps[w][quad * 4 + r][pcol] = f2bf(p);
                }
            }
            s8v aP[2];
            #pragma unroll
            for (int ks = 0; ks < 2; ++ks)
                aP[ks] = *(const s8v*)&lds_ps[w][i15][(ks * 32 + quad * 8) ^ ((i15 >> 2) << 4)];
            #pragma unroll
            for (int ntd = 0; ntd < 8; ++ntd) {
                #pragma unroll
                for (int ks = 0; ks < 2; ++ks) {
                    int row = ntd * 16 + i15;
                    int slot = row * 8 + ((ks * 4 + quad) ^ (row & 7));
                    s8v bV = *(const s8v*)&lds_vt[slot * 8];
                    accB[ntd] = __builtin_amdgcn_mfma_f32_16x16x32_bf16(aP[ks], bV, accB[ntd], 0, 0, 0);
                }
            }
        }
        __syncthreads();
    }

    // --- epilogue x2: reduce rowsums, normalize, +res, relu ---
    float invA[4], invB[4];
    #pragma unroll
    for (int r = 0; r < 4; ++r) {
        float sa = prsA[r];
        sa += __shfl_xor(sa, 1); sa += __shfl_xor(sa, 2);
        sa += __shfl_xor(sa, 4); sa += __shfl_xor(sa, 8);
        invA[r] = 1.0f / (sa + 1e-6f);
        float sb = prsB[r];
        sb += __shfl_xor(sb, 1); sb += __shfl_xor(sb, 2);
        sb += __shfl_xor(sb, 4); sb += __shfl_xor(sb, 8);
        invB[r] = 1.0f / (sb + 1e-6f);
    }
    #pragma unroll
    for (int ntd = 0; ntd < 8; ++ntd) {
        int dcol = h * HD + ntd * 16 + i15;
        #pragma unroll
        for (int r = 0; r < 4; ++r) {
            size_t idxA = ((size_t)b * LDIM + l0a + w * 16 + quad * 4 + r) * CDIM + dcol;
            float va = accA[ntd][r] * invA[r] + bf2f(resb[idxA]);
            out[idxA] = fmaxf(va, 0.f);
            size_t idxB = ((size_t)b * LDIM + l0b + w * 16 + quad * 4 + r) * CDIM + dcol;
            float vb = accB[ntd][r] * invB[r] + bf2f(resb[idxB]);
            out[idxB] = fmaxf(vb, 0.f);
        }
    }
}

// ---------------- launch ----------------
extern "C" void kernel_launch(void* const* d_in, const int* in_sizes, int n_in,
                              void* d_out, int out_size, void* d_ws, size_t ws_size,
                              hipStream_t stream) {
    (void)in_sizes; (void)n_in; (void)out_size; (void)ws_size;
    const float* x     = (const float*)d_in[0];
    const float* adj   = (const float*)d_in[1];
    const float* W_qkv = (const float*)d_in[2];
    const float* b_qkv = (const float*)d_in[3];
    const float* W_d   = (const float*)d_in[4];
    const float* b_d   = (const float*)d_in[5];
    float* out = (float*)d_out;

    char* ws = (char*)d_ws;
    size_t off = 0;
    u64* adjb   = (u64*)(ws + off);   off += (size_t)MROWS * 8 * 8;       // 512 KB
    u16*   xg   = (u16*)(ws + off);   off += (size_t)MROWS * CDIM * 2;    // 16 MB
    u16*   Wt   = (u16*)(ws + off);   off += (size_t)N3 * CDIM * 2;       // 6 MB
    u16*   ksig = (u16*)(ws + off);   off += (size_t)MROWS * CDIM * 2;    // 16 MB
    u16*   resb = (u16*)(ws + off);   off += (size_t)MROWS * CDIM * 2;    // 16 MB
    u16*   vt   = (u16*)(ws + off);   off += (size_t)MROWS * CDIM * 2;    // 16 MB

    prep_kernel<<<MROWS + (CDIM / 64) * (N3 / 64), 256, 0, stream>>>(
        adj, x, W_d, b_d, W_qkv, adjb, xg, Wt);
    gemm_bf16_kernel<<<dim3(N3 / 128, MROWS / 128), 256, 0, stream>>>(xg, Wt, b_qkv, ksig, resb, vt);
    attn_kernel<<<LDIM / 128 * NH * BDIM, 256, 0, stream>>>(ksig, vt, resb, adjb, out);
}